// Round 2
// baseline (364.648 us; speedup 1.0000x reference)
//
#include <hip/hip_runtime.h>
#include <hip/hip_bf16.h>

#define H_   16
#define N_   128
#define DIN  256
#define DK_  128
#define DG_  64

using bf16 = __hip_bfloat16;

__device__ __forceinline__ float bf2f(unsigned short u) {
    union { unsigned int i; float f; } c;
    c.i = ((unsigned int)u) << 16;
    return c.f;
}
__device__ __forceinline__ unsigned short f2bf(float f) {
    union { float f; unsigned int i; } c;
    c.f = f;
    unsigned int r = c.i + 0x7fffu + ((c.i >> 16) & 1u);  // RNE
    return (unsigned short)(r >> 16);
}

// generic element load: BF=1 -> buffer is bf16, BF=0 -> buffer is fp32
template<int BF>
__device__ __forceinline__ float lde(const void* p, int i) {
    if (BF) return bf2f(((const unsigned short*)p)[i]);
    else    return ((const float*)p)[i];
}

// ---------------- Kernel 0: dtype detection ----------------
// position_embedding is uniform [0,1). If bf16, low u16 of every 32-bit word
// is a bf16 in [0,1] => <= 0x3F80 (100%). If fp32, low u16 is random mantissa
// (~25% hit). Majority vote over 256 words.
__global__ void detect_kernel(const unsigned int* __restrict__ pos, int* __restrict__ flag) {
    if (threadIdx.x == 0 && blockIdx.x == 0) {
        int cnt = 0;
        for (int i = 0; i < 256; ++i) {
            unsigned int w = pos[i];
            if ((w & 0xffffu) <= 0x3F80u) cnt++;
        }
        *flag = (cnt >= 192) ? 1 : 0;
    }
}

// ---------------- Kernel 1: K/Q/V projections ----------------
// grid = 3*H*32 blocks (which, h, 4-row group), block = 128 threads (one per col)
template<int BF>
__global__ __launch_bounds__(128) void proj_kernel(
    const void* __restrict__ fa,
    const void* __restrict__ WK, const void* __restrict__ bk,
    const void* __restrict__ WQ, const void* __restrict__ bq,
    const void* __restrict__ WV, const void* __restrict__ bv,
    float* __restrict__ ws, const int* __restrict__ flag)
{
    if (flag[0] != BF) return;

    int bx = blockIdx.x;
    int which = bx / (H_ * 32);
    int rem = bx - which * (H_ * 32);
    int h = rem >> 5;
    int m0 = (rem & 31) * 4;
    int c = threadIdx.x;

    const void* W; const void* b; float* out;
    if (which == 0)      { W = WK; b = bk; out = ws; }
    else if (which == 1) { W = WQ; b = bq; out = ws + H_ * N_ * DK_; }
    else                 { W = WV; b = bv; out = ws + 2 * H_ * N_ * DK_; }

    __shared__ float fa_s[4][DIN];
    for (int i = threadIdx.x; i < 4 * DIN; i += 128) {
        int r = i >> 8, d = i & 255;
        fa_s[r][d] = lde<BF>(fa, (m0 + r) * DIN + d);
    }
    __syncthreads();

    int wbase = h * DIN * DK_ + c;
    float a0 = 0.f, a1 = 0.f, a2 = 0.f, a3 = 0.f;
    for (int d = 0; d < DIN; ++d) {
        float w = lde<BF>(W, wbase + d * DK_);
        a0 += fa_s[0][d] * w;
        a1 += fa_s[1][d] * w;
        a2 += fa_s[2][d] * w;
        a3 += fa_s[3][d] * w;
    }
    float bb = lde<BF>(b, h * DK_ + c);
    float* o = out + (h * N_ + m0) * DK_ + c;
    o[0 * DK_] = a0 + bb;
    o[1 * DK_] = a1 + bb;
    o[2 * DK_] = a2 + bb;
    o[3 * DK_] = a3 + bb;
}

// ---------------- Kernel 2: gate + score + softmax + colsum ----------------
// grid = H*N blocks (h,m), block = 128 threads (one per n)
template<int BF>
__global__ __launch_bounds__(128) void score_kernel(
    const void* __restrict__ pos,
    const void* __restrict__ WG, const void* __restrict__ bg,
    const float* __restrict__ ws, float* __restrict__ colsum,
    const int* __restrict__ flag)
{
    if (flag[0] != BF) return;

    int h = blockIdx.x >> 7;
    int m = blockIdx.x & 127;
    int n = threadIdx.x;

    __shared__ float wg_s[DG_];
    __shared__ float krow[DK_];
    __shared__ float redmax[2];
    __shared__ float redsum[2];

    if (n < DG_) wg_s[n] = lde<BF>(WG, h * DG_ + n);
    krow[n] = ws[(h * N_ + m) * DK_ + n];   // K region at ws offset 0
    __syncthreads();

    // geometric gate: relu(pos[m,n,:] . WG[h,:] + bg[h])
    float g = lde<BF>(bg, h);
    if (BF) {
        const uint4* pv = (const uint4*)((const unsigned short*)pos + (m * N_ + n) * DG_);
#pragma unroll
        for (int i = 0; i < 8; ++i) {
            uint4 u = pv[i];
            unsigned int uu[4] = { u.x, u.y, u.z, u.w };
#pragma unroll
            for (int j = 0; j < 4; ++j) {
                g += bf2f((unsigned short)(uu[j] & 0xffffu)) * wg_s[i * 8 + j * 2];
                g += bf2f((unsigned short)(uu[j] >> 16))     * wg_s[i * 8 + j * 2 + 1];
            }
        }
    } else {
        const float4* pv = (const float4*)((const float*)pos + (m * N_ + n) * DG_);
#pragma unroll
        for (int i = 0; i < 16; ++i) {
            float4 u = pv[i];
            g += u.x * wg_s[4 * i] + u.y * wg_s[4 * i + 1]
               + u.z * wg_s[4 * i + 2] + u.w * wg_s[4 * i + 3];
        }
    }
    float lg = logf(fmaxf(fmaxf(g, 0.0f), 1e-6f));

    // score: k[h,m,:] . q[h,n,:] / sqrt(DK)
    const float4* qv = (const float4*)(ws + H_ * N_ * DK_ + (h * N_ + n) * DK_);
    float s = 0.f;
#pragma unroll 8
    for (int i = 0; i < 32; ++i) {
        float4 q4 = qv[i];
        s += q4.x * krow[4 * i] + q4.y * krow[4 * i + 1]
           + q4.z * krow[4 * i + 2] + q4.w * krow[4 * i + 3];
    }
    float z = lg + s * 0.08838834764831845f;  // 1/sqrt(128)

    // softmax across the 128 threads (axis n)
    float v = z;
#pragma unroll
    for (int off = 32; off > 0; off >>= 1) v = fmaxf(v, __shfl_xor(v, off, 64));
    int wave = n >> 6;
    if ((n & 63) == 0) redmax[wave] = v;
    __syncthreads();
    float M = fmaxf(redmax[0], redmax[1]);
    float e = expf(z - M);
    float t = e;
#pragma unroll
    for (int off = 32; off > 0; off >>= 1) t += __shfl_xor(t, off, 64);
    if ((n & 63) == 0) redsum[wave] = t;
    __syncthreads();
    float S = redsum[0] + redsum[1];
    float w = e / S;

    atomicAdd(&colsum[h * DK_ + n], w);   // sum over m
}

// ---------------- Kernel 3: broadcast add + store ----------------
// out[n, h*128+c, d] = v[h,n,c]*colsum[h,c] + f_a[n,d]; 8 elems per thread
template<int BF>
__global__ __launch_bounds__(256) void out_kernel(
    const void* __restrict__ fa, const float* __restrict__ ws,
    const float* __restrict__ colsum, void* __restrict__ out,
    const int* __restrict__ flag)
{
    if (flag[0] != BF) return;

    int e = (blockIdx.x * 256 + threadIdx.x) * 8;   // elem idx, < 2^26
    int d0  = e & 255;
    int col = (e >> 8) & 2047;
    int n   = e >> 19;
    int h = col >> 7;
    int c = col & 127;

    const float* V = ws + 2 * H_ * N_ * DK_;
    float a = V[(h * N_ + n) * DK_ + c] * colsum[h * DK_ + c];

    if (BF) {
        uint4 u = *(const uint4*)((const unsigned short*)fa + n * DIN + d0);
        unsigned int uu[4] = { u.x, u.y, u.z, u.w };
        unsigned int rr[4];
#pragma unroll
        for (int j = 0; j < 4; ++j) {
            float lo = bf2f((unsigned short)(uu[j] & 0xffffu)) + a;
            float hi = bf2f((unsigned short)(uu[j] >> 16)) + a;
            rr[j] = (unsigned int)f2bf(lo) | ((unsigned int)f2bf(hi) << 16);
        }
        *(uint4*)((unsigned short*)out + e) = make_uint4(rr[0], rr[1], rr[2], rr[3]);
    } else {
        const float4* fv = (const float4*)((const float*)fa + n * DIN + d0);
        float4 u0 = fv[0], u1 = fv[1];
        u0.x += a; u0.y += a; u0.z += a; u0.w += a;
        u1.x += a; u1.y += a; u1.z += a; u1.w += a;
        float4* ov = (float4*)((float*)out + e);
        ov[0] = u0;
        ov[1] = u1;
    }
}

extern "C" void kernel_launch(void* const* d_in, const int* in_sizes, int n_in,
                              void* d_out, int out_size, void* d_ws, size_t ws_size,
                              hipStream_t stream)
{
    const void* fa  = d_in[0];
    const void* pos = d_in[1];
    const void* WG  = d_in[2];
    const void* bg  = d_in[3];
    const void* WK  = d_in[4];
    const void* bk  = d_in[5];
    const void* WQ  = d_in[6];
    const void* bq  = d_in[7];
    const void* WV  = d_in[8];
    const void* bv  = d_in[9];

    int*   flag = (int*)d_ws;
    float* buf  = (float*)d_ws + 16;                 // K | Q | V | colsum
    float* colsum = buf + 3 * H_ * N_ * DK_;         // 2048 floats

    hipLaunchKernelGGL(detect_kernel, dim3(1), dim3(64), 0, stream,
                       (const unsigned int*)pos, flag);

    hipLaunchKernelGGL((proj_kernel<0>), dim3(3 * H_ * 32), dim3(128), 0, stream,
                       fa, WK, bk, WQ, bq, WV, bv, buf, flag);
    hipLaunchKernelGGL((proj_kernel<1>), dim3(3 * H_ * 32), dim3(128), 0, stream,
                       fa, WK, bk, WQ, bq, WV, bv, buf, flag);

    hipMemsetAsync(colsum, 0, H_ * DK_ * sizeof(float), stream);

    hipLaunchKernelGGL((score_kernel<0>), dim3(H_ * N_), dim3(128), 0, stream,
                       pos, WG, bg, buf, colsum, flag);
    hipLaunchKernelGGL((score_kernel<1>), dim3(H_ * N_), dim3(128), 0, stream,
                       pos, WG, bg, buf, colsum, flag);

    const int nblk = (N_ * H_ * DK_ * DIN) / (8 * 256);
    hipLaunchKernelGGL((out_kernel<0>), dim3(nblk), dim3(256), 0, stream,
                       fa, buf, colsum, d_out, flag);
    hipLaunchKernelGGL((out_kernel<1>), dim3(nblk), dim3(256), 0, stream,
                       fa, buf, colsum, d_out, flag);
}

// Round 3
// 340.510 us; speedup vs baseline: 1.0709x; 1.0709x over previous
//
#include <hip/hip_runtime.h>
#include <hip/hip_bf16.h>

#define H_   16
#define N_   128
#define DIN  256
#define DK_  128
#define DG_  64
#define HNK  (H_ * N_ * DK_)

using bf16 = __hip_bfloat16;

__device__ __forceinline__ float bf2f(unsigned short u) {
    union { unsigned int i; float f; } c;
    c.i = ((unsigned int)u) << 16;
    return c.f;
}
__device__ __forceinline__ unsigned short f2bf(float f) {
    union { float f; unsigned int i; } c;
    c.f = f;
    unsigned int r = c.i + 0x7fffu + ((c.i >> 16) & 1u);  // RNE
    return (unsigned short)(r >> 16);
}

// generic element load: BF=1 -> buffer is bf16, BF=0 -> buffer is fp32
template<int BF>
__device__ __forceinline__ float lde(const void* p, int i) {
    if (BF) return bf2f(((const unsigned short*)p)[i]);
    else    return ((const float*)p)[i];
}

// ---------------- Kernel 0: dtype detect + colsum zero-init ----------------
// position_embedding is uniform [0,1). If bf16, low u16 of every 32-bit word
// is a bf16 in [0,1] => <= 0x3F80 (100% hit). If fp32, low u16 is random
// mantissa (~25% hit). Majority vote over 256 words, 64 lanes in parallel.
__global__ __launch_bounds__(64) void detect_init_kernel(
    const unsigned int* __restrict__ pos, int* __restrict__ flag,
    float* __restrict__ colsum)
{
    int t = threadIdx.x;
    int cnt = 0;
#pragma unroll
    for (int i = 0; i < 4; ++i) {
        unsigned int w = pos[t * 4 + i];
        cnt += ((w & 0xffffu) <= 0x3F80u) ? 1 : 0;
    }
#pragma unroll
    for (int off = 32; off > 0; off >>= 1) cnt += __shfl_xor(cnt, off, 64);
    if (t == 0) flag[0] = (cnt >= 192) ? 1 : 0;

    // zero colsum: 2048 floats = 512 float4
    float4 z = make_float4(0.f, 0.f, 0.f, 0.f);
    float4* cs = (float4*)colsum;
#pragma unroll
    for (int i = 0; i < 8; ++i) cs[t + 64 * i] = z;
}

// ---------------- Kernel 1: K/Q/V projections ----------------
template<int BF>
__device__ __forceinline__ void proj_body(
    const void* __restrict__ fa, const void* __restrict__ W,
    const void* __restrict__ b, float* __restrict__ out, int h, int m0)
{
    int c = threadIdx.x;
    __shared__ float fa_s[4][DIN];
    for (int i = threadIdx.x; i < 4 * DIN; i += 128) {
        int r = i >> 8, d = i & 255;
        fa_s[r][d] = lde<BF>(fa, (m0 + r) * DIN + d);
    }
    __syncthreads();

    int wbase = h * DIN * DK_ + c;
    float a0 = 0.f, a1 = 0.f, a2 = 0.f, a3 = 0.f;
    for (int d = 0; d < DIN; ++d) {
        float w = lde<BF>(W, wbase + d * DK_);
        a0 += fa_s[0][d] * w;
        a1 += fa_s[1][d] * w;
        a2 += fa_s[2][d] * w;
        a3 += fa_s[3][d] * w;
    }
    float bb = lde<BF>(b, h * DK_ + c);
    float* o = out + (h * N_ + m0) * DK_ + c;
    o[0 * DK_] = a0 + bb;
    o[1 * DK_] = a1 + bb;
    o[2 * DK_] = a2 + bb;
    o[3 * DK_] = a3 + bb;
}

// grid = 3*H*32 blocks (which, h, 4-row group), block = 128 threads (one per col)
__global__ __launch_bounds__(128) void proj_kernel(
    const void* __restrict__ fa,
    const void* __restrict__ WK, const void* __restrict__ bk,
    const void* __restrict__ WQ, const void* __restrict__ bq,
    const void* __restrict__ WV, const void* __restrict__ bv,
    float* __restrict__ ws, const int* __restrict__ flag)
{
    int bx = blockIdx.x;
    int which = bx / (H_ * 32);
    int rem = bx - which * (H_ * 32);
    int h = rem >> 5;
    int m0 = (rem & 31) * 4;

    const void* W; const void* b; float* out;
    if (which == 0)      { W = WK; b = bk; out = ws; }
    else if (which == 1) { W = WQ; b = bq; out = ws + HNK; }
    else                 { W = WV; b = bv; out = ws + 2 * HNK; }

    if (flag[0]) proj_body<1>(fa, W, b, out, h, m0);
    else         proj_body<0>(fa, W, b, out, h, m0);
}

// ---------------- Kernel 2: gate + score + softmax + colsum ----------------
template<int BF>
__device__ __forceinline__ void score_body(
    const void* __restrict__ pos, const void* __restrict__ WG,
    const void* __restrict__ bg, const float* __restrict__ ws,
    float* __restrict__ colsum, int h, int m)
{
    int n = threadIdx.x;
    __shared__ float wg_s[DG_];
    __shared__ float krow[DK_];
    __shared__ float redmax[2];
    __shared__ float redsum[2];

    if (n < DG_) wg_s[n] = lde<BF>(WG, h * DG_ + n);
    krow[n] = ws[(h * N_ + m) * DK_ + n];   // K region at ws offset 0
    __syncthreads();

    // geometric gate: relu(pos[m,n,:] . WG[h,:] + bg[h])
    float g = lde<BF>(bg, h);
    if (BF) {
        const uint4* pv = (const uint4*)((const unsigned short*)pos + (m * N_ + n) * DG_);
#pragma unroll
        for (int i = 0; i < 8; ++i) {
            uint4 u = pv[i];
            unsigned int uu[4] = { u.x, u.y, u.z, u.w };
#pragma unroll
            for (int j = 0; j < 4; ++j) {
                g += bf2f((unsigned short)(uu[j] & 0xffffu)) * wg_s[i * 8 + j * 2];
                g += bf2f((unsigned short)(uu[j] >> 16))     * wg_s[i * 8 + j * 2 + 1];
            }
        }
    } else {
        const float4* pv = (const float4*)((const float*)pos + (m * N_ + n) * DG_);
#pragma unroll
        for (int i = 0; i < 16; ++i) {
            float4 u = pv[i];
            g += u.x * wg_s[4 * i] + u.y * wg_s[4 * i + 1]
               + u.z * wg_s[4 * i + 2] + u.w * wg_s[4 * i + 3];
        }
    }
    float lg = logf(fmaxf(fmaxf(g, 0.0f), 1e-6f));

    // score: k[h,m,:] . q[h,n,:] / sqrt(DK)
    const float4* qv = (const float4*)(ws + HNK + (h * N_ + n) * DK_);
    float s = 0.f;
#pragma unroll 8
    for (int i = 0; i < 32; ++i) {
        float4 q4 = qv[i];
        s += q4.x * krow[4 * i] + q4.y * krow[4 * i + 1]
           + q4.z * krow[4 * i + 2] + q4.w * krow[4 * i + 3];
    }
    float z = lg + s * 0.08838834764831845f;  // 1/sqrt(128)

    // softmax across the 128 threads (axis n)
    float v = z;
#pragma unroll
    for (int off = 32; off > 0; off >>= 1) v = fmaxf(v, __shfl_xor(v, off, 64));
    int wave = n >> 6;
    if ((n & 63) == 0) redmax[wave] = v;
    __syncthreads();
    float M = fmaxf(redmax[0], redmax[1]);
    float e = expf(z - M);
    float t = e;
#pragma unroll
    for (int off = 32; off > 0; off >>= 1) t += __shfl_xor(t, off, 64);
    if ((n & 63) == 0) redsum[wave] = t;
    __syncthreads();
    float S = redsum[0] + redsum[1];
    float w = e / S;

    atomicAdd(&colsum[h * DK_ + n], w);   // sum over m
}

// grid = H*N blocks (h,m), block = 128 threads (one per n)
__global__ __launch_bounds__(128) void score_kernel(
    const void* __restrict__ pos,
    const void* __restrict__ WG, const void* __restrict__ bg,
    const float* __restrict__ ws, float* __restrict__ colsum,
    const int* __restrict__ flag)
{
    int h = blockIdx.x >> 7;
    int m = blockIdx.x & 127;
    if (flag[0]) score_body<1>(pos, WG, bg, ws, colsum, h, m);
    else         score_body<0>(pos, WG, bg, ws, colsum, h, m);
}

// ---------------- Kernel 3: broadcast add + store ----------------
// out[n, h*128+c, d] = v[h,n,c]*colsum[h,c] + f_a[n,d]; 8 elems per thread
__global__ __launch_bounds__(256) void out_kernel(
    const void* __restrict__ fa, const float* __restrict__ ws,
    const float* __restrict__ colsum, void* __restrict__ out,
    const int* __restrict__ flag)
{
    int e = (blockIdx.x * 256 + threadIdx.x) * 8;   // elem idx, < 2^26
    int d0  = e & 255;
    int col = (e >> 8) & 2047;
    int n   = e >> 19;
    int h = col >> 7;
    int c = col & 127;

    const float* V = ws + 2 * HNK;
    float a = V[(h * N_ + n) * DK_ + c] * colsum[h * DK_ + c];

    if (flag[0]) {
        uint4 u = *(const uint4*)((const unsigned short*)fa + n * DIN + d0);
        unsigned int uu[4] = { u.x, u.y, u.z, u.w };
        unsigned int rr[4];
#pragma unroll
        for (int j = 0; j < 4; ++j) {
            float lo = bf2f((unsigned short)(uu[j] & 0xffffu)) + a;
            float hi = bf2f((unsigned short)(uu[j] >> 16)) + a;
            rr[j] = (unsigned int)f2bf(lo) | ((unsigned int)f2bf(hi) << 16);
        }
        *(uint4*)((unsigned short*)out + e) = make_uint4(rr[0], rr[1], rr[2], rr[3]);
    } else {
        const float4* fv = (const float4*)((const float*)fa + n * DIN + d0);
        float4 u0 = fv[0], u1 = fv[1];
        u0.x += a; u0.y += a; u0.z += a; u0.w += a;
        u1.x += a; u1.y += a; u1.z += a; u1.w += a;
        float4* ov = (float4*)((float*)out + e);
        ov[0] = u0;
        ov[1] = u1;
    }
}

extern "C" void kernel_launch(void* const* d_in, const int* in_sizes, int n_in,
                              void* d_out, int out_size, void* d_ws, size_t ws_size,
                              hipStream_t stream)
{
    const void* fa  = d_in[0];
    const void* pos = d_in[1];
    const void* WG  = d_in[2];
    const void* bg  = d_in[3];
    const void* WK  = d_in[4];
    const void* bk  = d_in[5];
    const void* WQ  = d_in[6];
    const void* bq  = d_in[7];
    const void* WV  = d_in[8];
    const void* bv  = d_in[9];

    int*   flag = (int*)d_ws;
    float* buf  = (float*)d_ws + 16;          // K | Q | V
    float* colsum = buf + 3 * HNK;            // 2048 floats

    hipLaunchKernelGGL(detect_init_kernel, dim3(1), dim3(64), 0, stream,
                       (const unsigned int*)pos, flag, colsum);

    hipLaunchKernelGGL(proj_kernel, dim3(3 * H_ * 32), dim3(128), 0, stream,
                       fa, WK, bk, WQ, bq, WV, bv, buf, flag);

    hipLaunchKernelGGL(score_kernel, dim3(H_ * N_), dim3(128), 0, stream,
                       pos, WG, bg, buf, colsum, flag);

    const int nblk = (N_ * H_ * DK_ * DIN) / (8 * 256);
    hipLaunchKernelGGL(out_kernel, dim3(nblk), dim3(256), 0, stream,
                       fa, buf, colsum, d_out, flag);
}